// Round 9
// baseline (176.320 us; speedup 1.0000x reference)
//
#include <hip/hip_runtime.h>
#include <math.h>

#define C_CH 256
#define T_LEN 4096

// R9 = measurement probe: drive_scan launched 3x (idempotent) to expose its
// steady-state duration via dur_us delta (top-5 profile rows are censored by
// the harness's 43us d_ws poison fills). Drive structure = R7 (all 12 float4
// loads issued before the single barrier -> max outstanding VMEM) +
// __launch_bounds__(256,2) (room for ~90 live regs, no spills).
// No device-scope fences/atomics (R3/R4 lesson: per-block agent-release on
// gfx950's non-coherent per-XCD L2s serializes the whole dispatch).

__global__ __launch_bounds__(256, 2) void drive_scan_kernel(
    const float* __restrict__ x,
    const float* __restrict__ w3, const float* __restrict__ b3,
    const float* __restrict__ w5, const float* __restrict__ b5,
    const float* __restrict__ w9, const float* __restrict__ b9,
    const float* __restrict__ w_red, const float* __restrict__ b_red,
    const float* __restrict__ latency_scale,
    float* __restrict__ out_lat, float* __restrict__ out_act)
{
    const int blk  = blockIdx.x;       // b*256 + c
    const int b    = blk >> 8;
    const int c    = blk & 255;
    const int tid  = threadIdx.x;
    const int lane = tid & 63;
    const int wv   = tid >> 6;

    __shared__ float sWF[28];          // 27 folded taps + Beff at [27]
    __shared__ float sHalo[3][8][256]; // [r][0..3]=own first4, [4..7]=own last4
    __shared__ float sWaveTot[4];
    __shared__ float sCarry[4];
    __shared__ int   sMin[4];

    // --- exact-tile x loads: all 12 float4 issued up-front, no overlap ---
    const int t0 = tid << 4;                       // this thread's 16 steps
    float xv[3][16];
    #pragma unroll
    for (int r = 0; r < 3; ++r) {
        const int src = (3 * c + r) & 255;         // src row = (3c+r) mod 256
        const float4* p = (const float4*)(x + ((size_t)b * C_CH + src) * T_LEN + t0);
        #pragma unroll
        for (int v = 0; v < 4; ++v) {
            float4 q = p[v];
            xv[r][4 * v + 0] = q.x; xv[r][4 * v + 1] = q.y;
            xv[r][4 * v + 2] = q.z; xv[r][4 * v + 3] = q.w;
        }
        #pragma unroll
        for (int k = 0; k < 4; ++k) {
            sHalo[r][k][tid]     = xv[r][k];       // own first 4
            sHalo[r][4 + k][tid] = xv[r][12 + k];  // own last 4
        }
    }

    // --- parallel in-block weight fold (threads 0..27) ---
    if (tid < 27) {
        const int r = tid / 9, k = tid - 9 * r;
        const int q0     = 18 * c + 6 * r;
        const int region = (q0 >= 1536) + (q0 >= 3072);
        const int p0     = q0 - region * 1536;
        const int K      = (region == 0) ? 3 : (region == 1 ? 5 : 9);
        const int off    = (9 - K) >> 1;
        const float* wP  = (region == 0) ? w3 : (region == 1 ? w5 : w9);
        const int kk     = k - off;
        float w = 0.0f;
        if (kk >= 0 && kk < K) {
            const float* wr = w_red + c * 18 + 6 * r;
            #pragma unroll
            for (int j = 0; j < 6; ++j)
                w = fmaf(wr[j], wP[(p0 + j) * K + kk], w);
        }
        sWF[tid] = w;
    } else if (tid == 27) {
        float acc = b_red[c];
        #pragma unroll
        for (int r = 0; r < 3; ++r) {
            const int q0     = 18 * c + 6 * r;
            const int region = (q0 >= 1536) + (q0 >= 3072);
            const int p0     = q0 - region * 1536;
            const float* bP  = (region == 0) ? b3 : (region == 1 ? b5 : b9);
            const float* wr  = w_red + c * 18 + 6 * r;
            #pragma unroll
            for (int j = 0; j < 6; ++j) acc = fmaf(wr[j], bP[p0 + j], acc);
        }
        sWF[27] = acc;
    }
    __syncthreads();

    // --- drive: 27 FMA per t-step (bit-exact order: Beff, r asc, k asc) ---
    const float Beff = sWF[27];
    float d[16];
    #pragma unroll
    for (int tt = 0; tt < 16; ++tt) d[tt] = Beff;
    #pragma unroll
    for (int r = 0; r < 3; ++r) {
        float xa[24];                              // window [t0-4, t0+20)
        #pragma unroll
        for (int e = 0; e < 4; ++e)
            xa[e] = tid ? sHalo[r][4 + e][tid - 1] : 0.0f;          // left halo
        #pragma unroll
        for (int e = 0; e < 16; ++e) xa[4 + e] = xv[r][e];
        #pragma unroll
        for (int e = 0; e < 4; ++e)
            xa[20 + e] = (tid < 255) ? sHalo[r][e][tid + 1] : 0.0f; // right halo
        #pragma unroll
        for (int k = 0; k < 9; ++k) {
            const float wk = sWF[r * 9 + k];
            #pragma unroll
            for (int tt = 0; tt < 16; ++tt)
                d[tt] = fmaf(wk, xa[tt + k], d[tt]);
        }
    }

    const float A   = (float)0.8187307530779818;          // exp(-1/5), fp32
    const float OMA = (float)(1.0 - 0.8187307530779818);  // matches ref rounding

    // --- chunk-local scan: V after 16 steps from 0 ---
    float S = 0.0f;
    #pragma unroll
    for (int tt = 0; tt < 16; ++tt) S = A * S + OMA * d[tt];

    // --- wave-level weighted inclusive scan (per-chunk decay A^16) ---
    const float Fp[6] = {
        (float)4.0762203978366215e-02,  // A^16  = e^-3.2
        (float)1.6615572731739337e-03,  // A^32
        (float)2.7607725720371943e-06,  // A^64
        (float)7.6218649302532563e-12,  // A^128
        (float)5.8092835977683129e-23,  // A^256
        (float)3.3744728758705166e-45   // A^512 (denormal)
    };
    float cinc = S;
    #pragma unroll
    for (int s = 0; s < 6; ++s) {
        const int o = 1 << s;
        const float y = __shfl_up(cinc, o, 64);
        if (lane >= o) cinc = fmaf(Fp[s], y, cinc);
    }
    if (lane == 63) sWaveTot[wv] = cinc;
    __syncthreads();
    if (tid == 0) {
        // A^1024 underflows fp32 -> cross-wave decay factor is exactly 0
        float g = 0.0f;
        #pragma unroll
        for (int w = 0; w < 4; ++w) { sCarry[w] = g; g = sWaveTot[w]; }
    }
    __syncthreads();
    const float cprev = __shfl_up(cinc, 1, 64);
    const float Vin = (lane ? cprev : 0.0f)
                    + expf(-3.2f * (float)lane) * sCarry[wv];

    // --- replay chunk with true incoming V; first threshold crossing ---
    float V = Vin;
    int firstT = T_LEN;
    #pragma unroll
    for (int tt = 0; tt < 16; ++tt) {
        V = A * V + OMA * d[tt];
        if (V >= 1.0f && firstT == T_LEN) firstT = t0 + tt;
    }

    // --- block min-reduce ---
    #pragma unroll
    for (int o = 32; o > 0; o >>= 1)
        firstT = min(firstT, __shfl_xor(firstT, o, 64));
    if (lane == 0) sMin[wv] = firstT;
    __syncthreads();
    if (tid == 0) {
        const int f = min(min(sMin[0], sMin[1]), min(sMin[2], sMin[3]));
        const float lat   = (float)f;                          // T if never fired
        const float scale = fmaxf(latency_scale[0], 0.001f);
        out_lat[blk] = lat;
        out_act[blk] = expf(-lat / scale);
    }
}

// ---------------------------------------------------------------------------
// K2: gated mix + 2-layer MLP + softplus/clip. One block per batch row.
// og staged through padded LDS transpose tiles (coalesced global reads).
// ---------------------------------------------------------------------------
__global__ __launch_bounds__(256) void mlp_kernel(
    const float* __restrict__ act,
    const float* __restrict__ og, const float* __restrict__ bias,
    const float* __restrict__ W1, const float* __restrict__ b1,
    const float* __restrict__ W2, const float* __restrict__ b2,
    float* __restrict__ out_pred)
{
    const int b = blockIdx.x;
    const int j = threadIdx.x;
    __shared__ float sAct[256];
    __shared__ float sOg[32][257];     // i-tile x j, +1 pad breaks conflicts
    __shared__ float sMix[256];
    __shared__ float sH[128];

    sAct[j] = act[b * 256 + j];

    // mixed[j] = bias[j] + sum_i act[i] * og[j,i], i-tiled through LDS.
    float mix = bias[j];
    for (int i0 = 0; i0 < 256; i0 += 32) {
        __syncthreads();               // protect previous tile's readers
        #pragma unroll
        for (int m = 0; m < 32; ++m) {
            const int f  = (m << 8) + j;
            const int jj = f >> 5;
            const int ii = f & 31;
            sOg[ii][jj] = og[jj * 256 + i0 + ii];
        }
        __syncthreads();
        #pragma unroll
        for (int ii = 0; ii < 32; ++ii)
            mix = fmaf(sAct[i0 + ii], sOg[ii][j], mix);
    }
    sMix[j] = mix;
    __syncthreads();

    // h[j] = relu(b1[j] + sum_i mixed[i] * W1[i,j]);  W1 (256,128) row-major
    if (j < 128) {
        float h = b1[j];
        #pragma unroll 8
        for (int i = 0; i < 256; ++i) h = fmaf(sMix[i], W1[i * 128 + j], h);
        sH[j] = fmaxf(h, 0.0f);
    }
    __syncthreads();

    // raw[j] = b2[j] + sum_k h[k] * W2[k,j];  W2 (128,256) row-major
    float raw = b2[j];
    #pragma unroll 8
    for (int k = 0; k < 128; ++k) raw = fmaf(sH[k], W2[k * 256 + j], raw);

    const float sp = fmaxf(raw, 0.0f) + log1pf(expf(-fabsf(raw)));
    out_pred[b * 256 + j] = fminf(fmaxf(sp, 0.0f), 4096.0f);
}

// ---------------------------------------------------------------------------
extern "C" void kernel_launch(void* const* d_in, const int* in_sizes, int n_in,
                              void* d_out, int out_size, void* d_ws, size_t ws_size,
                              hipStream_t stream) {
    const float* x    = (const float*)d_in[0];
    const float* w3   = (const float*)d_in[1];
    const float* b3   = (const float*)d_in[2];
    const float* w5   = (const float*)d_in[3];
    const float* b5   = (const float*)d_in[4];
    const float* w9   = (const float*)d_in[5];
    const float* b9   = (const float*)d_in[6];
    const float* wred = (const float*)d_in[7];
    const float* bred = (const float*)d_in[8];
    const float* ls   = (const float*)d_in[9];
    const float* og   = (const float*)d_in[10];
    const float* bias = (const float*)d_in[11];
    const float* W1   = (const float*)d_in[12];
    const float* b1   = (const float*)d_in[13];
    const float* W2   = (const float*)d_in[14];
    const float* b2   = (const float*)d_in[15];

    float* out      = (float*)d_out;
    float* out_pred = out;              // (8,256)
    float* out_lat  = out + 2048;       // (8,256)
    float* out_act  = out + 4096;       // (8,256)

    // PROBE: 3 identical drive launches (idempotent). dur delta vs R8 (137.4)
    // = 2x warm drive time. Remove the extra launches next round.
    drive_scan_kernel<<<2048, 256, 0, stream>>>(
        x, w3, b3, w5, b5, w9, b9, wred, bred, ls, out_lat, out_act);
    drive_scan_kernel<<<2048, 256, 0, stream>>>(
        x, w3, b3, w5, b5, w9, b9, wred, bred, ls, out_lat, out_act);
    drive_scan_kernel<<<2048, 256, 0, stream>>>(
        x, w3, b3, w5, b5, w9, b9, wred, bred, ls, out_lat, out_act);
    mlp_kernel<<<8, 256, 0, stream>>>(out_act, og, bias, W1, b1, W2, b2, out_pred);
}

// Round 10
// 130.548 us; speedup vs baseline: 1.3506x; 1.3506x over previous
//
#include <hip/hip_runtime.h>
#include <math.h>

#define C_CH 256
#define T_LEN 4096

// R10: attack the two measured consumers (R9 probe: drive=19.5us, mlp~30us).
// - drive: 512 thr x 8 steps -> ~30 live floats, launch_bounds(512,8) ->
//   32 waves/CU (was 8). Double-buffered per-r halo LDS (33 KB).
// - 8 extra blocks prefetch og/W1/W2 (512 KB) into LLC during drive.
//   No fences/atomics/spins (R3/R4 lesson: agent-release fences serialize).
// - mlp: unroll-32 W1/W2 loads (were latency chains of unroll-8).

__global__ __launch_bounds__(512, 8) void drive_scan_kernel(
    const float* __restrict__ x,
    const float* __restrict__ w3, const float* __restrict__ b3,
    const float* __restrict__ w5, const float* __restrict__ b5,
    const float* __restrict__ w9, const float* __restrict__ b9,
    const float* __restrict__ w_red, const float* __restrict__ b_red,
    const float* __restrict__ latency_scale,
    const float* __restrict__ og, const float* __restrict__ W1,
    const float* __restrict__ W2, float* __restrict__ sink,
    float* __restrict__ out_lat, float* __restrict__ out_act)
{
    const int blk = blockIdx.x;
    const int tid = threadIdx.x;

    if (blk >= 2048) {
        // --- LLC prefetch of MLP weights, overlapped with drive ---
        const int id = (blk - 2048) * 512 + tid;   // 0..4095
        float acc = 0.0f;
        const float4* og4 = (const float4*)og;     // 16384 float4
        const float4* W14 = (const float4*)W1;     // 8192 float4
        const float4* W24 = (const float4*)W2;     // 8192 float4
        #pragma unroll
        for (int v = 0; v < 4; ++v) {
            float4 q = og4[id + v * 4096]; acc += q.x + q.y + q.z + q.w;
        }
        #pragma unroll
        for (int v = 0; v < 2; ++v) {
            float4 q = W14[id + v * 4096]; acc += q.x + q.y + q.z + q.w;
        }
        #pragma unroll
        for (int v = 0; v < 2; ++v) {
            float4 q = W24[id + v * 4096]; acc += q.x + q.y + q.z + q.w;
        }
        sink[id] = acc;                            // keep loads alive
        return;
    }

    const int b    = blk >> 8;
    const int c    = blk & 255;
    const int lane = tid & 63;
    const int wv   = tid >> 6;                     // 0..7

    __shared__ float sWF[28];                      // 27 folded taps + Beff
    __shared__ float sHalo[2][8][512];             // double-buffered own 8
    __shared__ float sWaveTot[8];
    __shared__ float sCarry[8];
    __shared__ int   sMin[8];

    // --- parallel in-block weight fold (threads 0..27); covered by r=0 barrier
    if (tid < 27) {
        const int r = tid / 9, k = tid - 9 * r;
        const int q0     = 18 * c + 6 * r;
        const int region = (q0 >= 1536) + (q0 >= 3072);
        const int p0     = q0 - region * 1536;
        const int K      = (region == 0) ? 3 : (region == 1 ? 5 : 9);
        const int off    = (9 - K) >> 1;
        const float* wP  = (region == 0) ? w3 : (region == 1 ? w5 : w9);
        const int kk     = k - off;
        float w = 0.0f;
        if (kk >= 0 && kk < K) {
            const float* wr = w_red + c * 18 + 6 * r;
            #pragma unroll
            for (int j = 0; j < 6; ++j)
                w = fmaf(wr[j], wP[(p0 + j) * K + kk], w);
        }
        sWF[tid] = w;
    } else if (tid == 27) {
        float acc = b_red[c];
        #pragma unroll
        for (int r = 0; r < 3; ++r) {
            const int q0     = 18 * c + 6 * r;
            const int region = (q0 >= 1536) + (q0 >= 3072);
            const int p0     = q0 - region * 1536;
            const float* bP  = (region == 0) ? b3 : (region == 1 ? b5 : b9);
            const float* wr  = w_red + c * 18 + 6 * r;
            #pragma unroll
            for (int j = 0; j < 6; ++j) acc = fmaf(wr[j], bP[p0 + j], acc);
        }
        sWF[27] = acc;
    }

    // --- per-r: load own 8 floats, share via LDS, 9-tap FMA into d[8] ---
    const int t0 = tid << 3;                       // this thread's 8 steps
    float d[8];
    float Beff;
    #pragma unroll
    for (int r = 0; r < 3; ++r) {
        const int buf = r & 1;
        const int src = (3 * c + r) & 255;         // src row = (3c+r) mod 256
        const float4* p = (const float4*)(x + ((size_t)b * C_CH + src) * T_LEN + t0);
        float xa[16];                              // window [t0-4, t0+12)
        {
            float4 q0 = p[0], q1 = p[1];
            xa[4] = q0.x; xa[5] = q0.y; xa[6]  = q0.z; xa[7]  = q0.w;
            xa[8] = q1.x; xa[9] = q1.y; xa[10] = q1.z; xa[11] = q1.w;
        }
        #pragma unroll
        for (int e = 0; e < 8; ++e) sHalo[buf][e][tid] = xa[4 + e];
        __syncthreads();   // r=0: also publishes sWF. 1 barrier/r; double
                           // buffer removes the WAR hazard (r+2 reuses buf
                           // only after the r+1 barrier).
        if (r == 0) {
            Beff = sWF[27];
            #pragma unroll
            for (int tt = 0; tt < 8; ++tt) d[tt] = Beff;
        }
        #pragma unroll
        for (int e = 0; e < 4; ++e)
            xa[e] = tid ? sHalo[buf][4 + e][tid - 1] : 0.0f;           // left
        #pragma unroll
        for (int e = 0; e < 4; ++e)
            xa[12 + e] = (tid < 511) ? sHalo[buf][e][tid + 1] : 0.0f;  // right
        #pragma unroll
        for (int k = 0; k < 9; ++k) {
            const float wk = sWF[r * 9 + k];
            #pragma unroll
            for (int tt = 0; tt < 8; ++tt)
                d[tt] = fmaf(wk, xa[tt + k], d[tt]);
        }
    }

    const float A   = (float)0.8187307530779818;          // exp(-1/5), fp32
    const float OMA = (float)(1.0 - 0.8187307530779818);  // matches ref rounding

    // --- chunk-local scan: V after 8 steps from 0 ---
    float S = 0.0f;
    #pragma unroll
    for (int tt = 0; tt < 8; ++tt) S = A * S + OMA * d[tt];

    // --- wave-level weighted inclusive scan (per-chunk decay A^8) ---
    const float Fp[6] = {
        (float)2.0189651799465541e-01,  // A^8   = e^-1.6
        (float)4.0762203978366215e-02,  // A^16
        (float)1.6615572731739337e-03,  // A^32
        (float)2.7607725720371943e-06,  // A^64
        (float)7.6218649302532563e-12,  // A^128
        (float)5.8092835977683129e-23   // A^256
    };
    float cinc = S;
    #pragma unroll
    for (int s = 0; s < 6; ++s) {
        const int o = 1 << s;
        const float y = __shfl_up(cinc, o, 64);
        if (lane >= o) cinc = fmaf(Fp[s], y, cinc);
    }
    if (lane == 63) sWaveTot[wv] = cinc;
    __syncthreads();
    if (tid == 0) {
        // cross-wave decay A^512 ~ 3.4e-45 (denormal ~ 0)
        const float A512 = 3.3744728758705166e-45f;
        float g = 0.0f;
        #pragma unroll
        for (int w = 0; w < 8; ++w) { sCarry[w] = g; g = sWaveTot[w] + A512 * g; }
    }
    __syncthreads();
    const float cprev = __shfl_up(cinc, 1, 64);
    const float Vin = (lane ? cprev : 0.0f)
                    + expf(-1.6f * (float)lane) * sCarry[wv];

    // --- replay chunk with true incoming V; first threshold crossing ---
    float V = Vin;
    int firstT = T_LEN;
    #pragma unroll
    for (int tt = 0; tt < 8; ++tt) {
        V = A * V + OMA * d[tt];
        if (V >= 1.0f && firstT == T_LEN) firstT = t0 + tt;
    }

    // --- block min-reduce ---
    #pragma unroll
    for (int o = 32; o > 0; o >>= 1)
        firstT = min(firstT, __shfl_xor(firstT, o, 64));
    if (lane == 0) sMin[wv] = firstT;
    __syncthreads();
    if (tid == 0) {
        int f = sMin[0];
        #pragma unroll
        for (int w = 1; w < 8; ++w) f = min(f, sMin[w]);
        const float lat   = (float)f;                          // T if never fired
        const float scale = fmaxf(latency_scale[0], 0.001f);
        out_lat[blk] = lat;
        out_act[blk] = expf(-lat / scale);
    }
}

// ---------------------------------------------------------------------------
// K2: gated mix + 2-layer MLP + softplus/clip. One block per batch row.
// Weights LLC-warm from the drive-phase prefetch blocks. og via padded LDS
// transpose tiles; W1/W2 coalesced with unroll-32 (32 loads in flight).
// ---------------------------------------------------------------------------
__global__ __launch_bounds__(256) void mlp_kernel(
    const float* __restrict__ act,
    const float* __restrict__ og, const float* __restrict__ bias,
    const float* __restrict__ W1, const float* __restrict__ b1,
    const float* __restrict__ W2, const float* __restrict__ b2,
    float* __restrict__ out_pred)
{
    const int b = blockIdx.x;
    const int j = threadIdx.x;
    __shared__ float sAct[256];
    __shared__ float sOg[32][257];     // i-tile x j, +1 pad breaks conflicts
    __shared__ float sMix[256];
    __shared__ float sH[128];

    sAct[j] = act[b * 256 + j];

    // mixed[j] = bias[j] + sum_i act[i] * og[j,i], i-tiled through LDS.
    float mix = bias[j];
    for (int i0 = 0; i0 < 256; i0 += 32) {
        __syncthreads();               // protect previous tile's readers
        #pragma unroll
        for (int m = 0; m < 32; ++m) {
            const int f  = (m << 8) + j;
            const int jj = f >> 5;
            const int ii = f & 31;
            sOg[ii][jj] = og[jj * 256 + i0 + ii];
        }
        __syncthreads();
        #pragma unroll
        for (int ii = 0; ii < 32; ++ii)
            mix = fmaf(sAct[i0 + ii], sOg[ii][j], mix);
    }
    sMix[j] = mix;
    __syncthreads();

    // h[j] = relu(b1[j] + sum_i mixed[i] * W1[i,j]);  W1 (256,128) row-major
    if (j < 128) {
        float h = b1[j];
        #pragma unroll 32
        for (int i = 0; i < 256; ++i) h = fmaf(sMix[i], W1[i * 128 + j], h);
        sH[j] = fmaxf(h, 0.0f);
    }
    __syncthreads();

    // raw[j] = b2[j] + sum_k h[k] * W2[k,j];  W2 (128,256) row-major
    float raw = b2[j];
    #pragma unroll 32
    for (int k = 0; k < 128; ++k) raw = fmaf(sH[k], W2[k * 256 + j], raw);

    const float sp = fmaxf(raw, 0.0f) + log1pf(expf(-fabsf(raw)));
    out_pred[b * 256 + j] = fminf(fmaxf(sp, 0.0f), 4096.0f);
}

// ---------------------------------------------------------------------------
extern "C" void kernel_launch(void* const* d_in, const int* in_sizes, int n_in,
                              void* d_out, int out_size, void* d_ws, size_t ws_size,
                              hipStream_t stream) {
    const float* x    = (const float*)d_in[0];
    const float* w3   = (const float*)d_in[1];
    const float* b3   = (const float*)d_in[2];
    const float* w5   = (const float*)d_in[3];
    const float* b5   = (const float*)d_in[4];
    const float* w9   = (const float*)d_in[5];
    const float* b9   = (const float*)d_in[6];
    const float* wred = (const float*)d_in[7];
    const float* bred = (const float*)d_in[8];
    const float* ls   = (const float*)d_in[9];
    const float* og   = (const float*)d_in[10];
    const float* bias = (const float*)d_in[11];
    const float* W1   = (const float*)d_in[12];
    const float* b1   = (const float*)d_in[13];
    const float* W2   = (const float*)d_in[14];
    const float* b2   = (const float*)d_in[15];

    float* sink     = (float*)d_ws;     // prefetch sink (4096 floats)
    float* out      = (float*)d_out;
    float* out_pred = out;              // (8,256)
    float* out_lat  = out + 2048;       // (8,256)
    float* out_act  = out + 4096;       // (8,256)

    drive_scan_kernel<<<2056, 512, 0, stream>>>(
        x, w3, b3, w5, b5, w9, b9, wred, bred, ls,
        og, W1, W2, sink, out_lat, out_act);
    mlp_kernel<<<8, 256, 0, stream>>>(out_act, og, bias, W1, b1, W2, b2, out_pred);
}

// Round 11
// 125.611 us; speedup vs baseline: 1.4037x; 1.0393x over previous
//
#include <hip/hip_runtime.h>
#include <math.h>

#define C_CH 256
#define T_LEN 4096

// R11: drive unchanged (R10: 512thr x 8 steps, 32 waves/CU, dbuf halo LDS,
// 8 prefetch blocks warming og/W1/W2 into LLC). mlp restructured to 512
// threads with split reductions: og 2x128-i groups (4 tile rounds), W1 4
// partials per j (one 64-deep load round), W2 2 partials per j.
// No device-scope fences/atomics anywhere (R3/R4: per-block agent-release
// fences on gfx950's non-coherent per-XCD L2s serialized the dispatch).

__global__ __launch_bounds__(512, 8) void drive_scan_kernel(
    const float* __restrict__ x,
    const float* __restrict__ w3, const float* __restrict__ b3,
    const float* __restrict__ w5, const float* __restrict__ b5,
    const float* __restrict__ w9, const float* __restrict__ b9,
    const float* __restrict__ w_red, const float* __restrict__ b_red,
    const float* __restrict__ latency_scale,
    const float* __restrict__ og, const float* __restrict__ W1,
    const float* __restrict__ W2, float* __restrict__ sink,
    float* __restrict__ out_lat, float* __restrict__ out_act)
{
    const int blk = blockIdx.x;
    const int tid = threadIdx.x;

    if (blk >= 2048) {
        // --- LLC prefetch of MLP weights, overlapped with drive ---
        const int id = (blk - 2048) * 512 + tid;   // 0..4095
        float acc = 0.0f;
        const float4* og4 = (const float4*)og;     // 16384 float4
        const float4* W14 = (const float4*)W1;     // 8192 float4
        const float4* W24 = (const float4*)W2;     // 8192 float4
        #pragma unroll
        for (int v = 0; v < 4; ++v) {
            float4 q = og4[id + v * 4096]; acc += q.x + q.y + q.z + q.w;
        }
        #pragma unroll
        for (int v = 0; v < 2; ++v) {
            float4 q = W14[id + v * 4096]; acc += q.x + q.y + q.z + q.w;
        }
        #pragma unroll
        for (int v = 0; v < 2; ++v) {
            float4 q = W24[id + v * 4096]; acc += q.x + q.y + q.z + q.w;
        }
        sink[id] = acc;                            // keep loads alive
        return;
    }

    const int b    = blk >> 8;
    const int c    = blk & 255;
    const int lane = tid & 63;
    const int wv   = tid >> 6;                     // 0..7

    __shared__ float sWF[28];                      // 27 folded taps + Beff
    __shared__ float sHalo[2][8][512];             // double-buffered own 8
    __shared__ float sWaveTot[8];
    __shared__ float sCarry[8];
    __shared__ int   sMin[8];

    // --- parallel in-block weight fold (threads 0..27); covered by r=0 barrier
    if (tid < 27) {
        const int r = tid / 9, k = tid - 9 * r;
        const int q0     = 18 * c + 6 * r;
        const int region = (q0 >= 1536) + (q0 >= 3072);
        const int p0     = q0 - region * 1536;
        const int K      = (region == 0) ? 3 : (region == 1 ? 5 : 9);
        const int off    = (9 - K) >> 1;
        const float* wP  = (region == 0) ? w3 : (region == 1 ? w5 : w9);
        const int kk     = k - off;
        float w = 0.0f;
        if (kk >= 0 && kk < K) {
            const float* wr = w_red + c * 18 + 6 * r;
            #pragma unroll
            for (int j = 0; j < 6; ++j)
                w = fmaf(wr[j], wP[(p0 + j) * K + kk], w);
        }
        sWF[tid] = w;
    } else if (tid == 27) {
        float acc = b_red[c];
        #pragma unroll
        for (int r = 0; r < 3; ++r) {
            const int q0     = 18 * c + 6 * r;
            const int region = (q0 >= 1536) + (q0 >= 3072);
            const int p0     = q0 - region * 1536;
            const float* bP  = (region == 0) ? b3 : (region == 1 ? b5 : b9);
            const float* wr  = w_red + c * 18 + 6 * r;
            #pragma unroll
            for (int j = 0; j < 6; ++j) acc = fmaf(wr[j], bP[p0 + j], acc);
        }
        sWF[27] = acc;
    }

    // --- per-r: load own 8 floats, share via LDS, 9-tap FMA into d[8] ---
    const int t0 = tid << 3;                       // this thread's 8 steps
    float d[8];
    float Beff;
    #pragma unroll
    for (int r = 0; r < 3; ++r) {
        const int buf = r & 1;
        const int src = (3 * c + r) & 255;         // src row = (3c+r) mod 256
        const float4* p = (const float4*)(x + ((size_t)b * C_CH + src) * T_LEN + t0);
        float xa[16];                              // window [t0-4, t0+12)
        {
            float4 q0 = p[0], q1 = p[1];
            xa[4] = q0.x; xa[5] = q0.y; xa[6]  = q0.z; xa[7]  = q0.w;
            xa[8] = q1.x; xa[9] = q1.y; xa[10] = q1.z; xa[11] = q1.w;
        }
        #pragma unroll
        for (int e = 0; e < 8; ++e) sHalo[buf][e][tid] = xa[4 + e];
        __syncthreads();   // r=0: also publishes sWF; dbuf kills WAR hazard
        if (r == 0) {
            Beff = sWF[27];
            #pragma unroll
            for (int tt = 0; tt < 8; ++tt) d[tt] = Beff;
        }
        #pragma unroll
        for (int e = 0; e < 4; ++e)
            xa[e] = tid ? sHalo[buf][4 + e][tid - 1] : 0.0f;           // left
        #pragma unroll
        for (int e = 0; e < 4; ++e)
            xa[12 + e] = (tid < 511) ? sHalo[buf][e][tid + 1] : 0.0f;  // right
        #pragma unroll
        for (int k = 0; k < 9; ++k) {
            const float wk = sWF[r * 9 + k];
            #pragma unroll
            for (int tt = 0; tt < 8; ++tt)
                d[tt] = fmaf(wk, xa[tt + k], d[tt]);
        }
    }

    const float A   = (float)0.8187307530779818;          // exp(-1/5), fp32
    const float OMA = (float)(1.0 - 0.8187307530779818);  // matches ref rounding

    // --- chunk-local scan: V after 8 steps from 0 ---
    float S = 0.0f;
    #pragma unroll
    for (int tt = 0; tt < 8; ++tt) S = A * S + OMA * d[tt];

    // --- wave-level weighted inclusive scan (per-chunk decay A^8) ---
    const float Fp[6] = {
        (float)2.0189651799465541e-01,  // A^8   = e^-1.6
        (float)4.0762203978366215e-02,  // A^16
        (float)1.6615572731739337e-03,  // A^32
        (float)2.7607725720371943e-06,  // A^64
        (float)7.6218649302532563e-12,  // A^128
        (float)5.8092835977683129e-23   // A^256
    };
    float cinc = S;
    #pragma unroll
    for (int s = 0; s < 6; ++s) {
        const int o = 1 << s;
        const float y = __shfl_up(cinc, o, 64);
        if (lane >= o) cinc = fmaf(Fp[s], y, cinc);
    }
    if (lane == 63) sWaveTot[wv] = cinc;
    __syncthreads();
    if (tid == 0) {
        // cross-wave decay A^512 ~ 3.4e-45 (denormal ~ 0)
        const float A512 = 3.3744728758705166e-45f;
        float g = 0.0f;
        #pragma unroll
        for (int w = 0; w < 8; ++w) { sCarry[w] = g; g = sWaveTot[w] + A512 * g; }
    }
    __syncthreads();
    const float cprev = __shfl_up(cinc, 1, 64);
    const float Vin = (lane ? cprev : 0.0f)
                    + expf(-1.6f * (float)lane) * sCarry[wv];

    // --- replay chunk with true incoming V; first threshold crossing ---
    float V = Vin;
    int firstT = T_LEN;
    #pragma unroll
    for (int tt = 0; tt < 8; ++tt) {
        V = A * V + OMA * d[tt];
        if (V >= 1.0f && firstT == T_LEN) firstT = t0 + tt;
    }

    // --- block min-reduce ---
    #pragma unroll
    for (int o = 32; o > 0; o >>= 1)
        firstT = min(firstT, __shfl_xor(firstT, o, 64));
    if (lane == 0) sMin[wv] = firstT;
    __syncthreads();
    if (tid == 0) {
        int f = sMin[0];
        #pragma unroll
        for (int w = 1; w < 8; ++w) f = min(f, sMin[w]);
        const float lat   = (float)f;                          // T if never fired
        const float scale = fmaxf(latency_scale[0], 0.001f);
        out_lat[blk] = lat;
        out_act[blk] = expf(-lat / scale);
    }
}

// ---------------------------------------------------------------------------
// K2: gated mix + 2-layer MLP + softplus/clip. One 512-thread block per
// batch row; every phase uses split reductions so the dependent-load chains
// collapse to 1-2 latency rounds. Weights LLC-warm from drive-phase prefetch.
// ---------------------------------------------------------------------------
__global__ __launch_bounds__(512) void mlp_kernel(
    const float* __restrict__ act,
    const float* __restrict__ og, const float* __restrict__ bias,
    const float* __restrict__ W1, const float* __restrict__ b1,
    const float* __restrict__ W2, const float* __restrict__ b2,
    float* __restrict__ out_pred)
{
    const int b = blockIdx.x;
    const int t = threadIdx.x;
    const int j = t & 255;             // output index for og/W2 phases
    const int g = t >> 8;              // reduction group 0/1

    __shared__ float sAct[256];
    __shared__ float sOg[2][32][257];  // per-group transpose tile (+1 pad)
    __shared__ float sP[2][256];       // og partials
    __shared__ float sMix[256];
    __shared__ float sPH[4][128];      // W1 partials
    __shared__ float sH[128];
    __shared__ float sPR[2][256];      // W2 partials

    if (t < 256) sAct[t] = act[b * 256 + t];

    // mixed[j] = bias[j] + sum_i act[i]*og[j,i]; group g covers i in
    // [g*128, g*128+128) via 4 LDS transpose tiles of 32 i's.
    float mix = 0.0f;
    for (int m = 0; m < 4; ++m) {
        const int i0 = g * 128 + m * 32;
        __syncthreads();               // protect previous tile's readers
        // tile load: 32x256 elements by this group's 256 threads (32 each);
        // flat f = q*256 + j -> jj=f>>5, ii=f&31: coalesced 128B runs.
        #pragma unroll
        for (int q = 0; q < 32; ++q) {
            const int f  = (q << 8) + j;
            const int jj = f >> 5;
            const int ii = f & 31;
            sOg[g][ii][jj] = og[jj * 256 + i0 + ii];
        }
        __syncthreads();
        #pragma unroll
        for (int ii = 0; ii < 32; ++ii)
            mix = fmaf(sAct[i0 + ii], sOg[g][ii][j], mix);
    }
    sP[g][j] = mix;
    __syncthreads();
    if (t < 256) sMix[t] = bias[t] + sP[0][t] + sP[1][t];
    __syncthreads();

    // h[j1] = relu(b1 + sum_i mixed[i]*W1[i,j1]); 4 partials per j1, each a
    // fully-unrolled 64-load round. W1 (256,128) row-major: lanes span 64
    // consecutive j1 -> coalesced.
    {
        const int j1  = t & 127;
        const int seg = t >> 7;        // 0..3
        float h = 0.0f;
        #pragma unroll
        for (int ii = 0; ii < 64; ++ii) {
            const int i = seg * 64 + ii;
            h = fmaf(sMix[i], W1[i * 128 + j1], h);
        }
        sPH[seg][j1] = h;
    }
    __syncthreads();
    if (t < 128)
        sH[t] = fmaxf(b1[t] + ((sPH[0][t] + sPH[1][t]) + (sPH[2][t] + sPH[3][t])), 0.0f);
    __syncthreads();

    // raw[j] = b2[j] + sum_k h[k]*W2[k,j]; 2 partials per j, 64-load rounds.
    {
        float raw = 0.0f;
        #pragma unroll
        for (int kk = 0; kk < 64; ++kk) {
            const int k = g * 64 + kk;
            raw = fmaf(sH[k], W2[k * 256 + j], raw);
        }
        sPR[g][j] = raw;
    }
    __syncthreads();
    if (t < 256) {
        const float r  = b2[t] + sPR[0][t] + sPR[1][t];
        const float sp = fmaxf(r, 0.0f) + log1pf(expf(-fabsf(r)));
        out_pred[b * 256 + t] = fminf(fmaxf(sp, 0.0f), 4096.0f);
    }
}

// ---------------------------------------------------------------------------
extern "C" void kernel_launch(void* const* d_in, const int* in_sizes, int n_in,
                              void* d_out, int out_size, void* d_ws, size_t ws_size,
                              hipStream_t stream) {
    const float* x    = (const float*)d_in[0];
    const float* w3   = (const float*)d_in[1];
    const float* b3   = (const float*)d_in[2];
    const float* w5   = (const float*)d_in[3];
    const float* b5   = (const float*)d_in[4];
    const float* w9   = (const float*)d_in[5];
    const float* b9   = (const float*)d_in[6];
    const float* wred = (const float*)d_in[7];
    const float* bred = (const float*)d_in[8];
    const float* ls   = (const float*)d_in[9];
    const float* og   = (const float*)d_in[10];
    const float* bias = (const float*)d_in[11];
    const float* W1   = (const float*)d_in[12];
    const float* b1   = (const float*)d_in[13];
    const float* W2   = (const float*)d_in[14];
    const float* b2   = (const float*)d_in[15];

    float* sink     = (float*)d_ws;     // prefetch sink (4096 floats)
    float* out      = (float*)d_out;
    float* out_pred = out;              // (8,256)
    float* out_lat  = out + 2048;       // (8,256)
    float* out_act  = out + 4096;       // (8,256)

    drive_scan_kernel<<<2056, 512, 0, stream>>>(
        x, w3, b3, w5, b5, w9, b9, wred, bred, ls,
        og, W1, W2, sink, out_lat, out_act);
    mlp_kernel<<<8, 512, 0, stream>>>(out_act, og, bias, W1, b1, W2, b2, out_pred);
}